// Round 5
// baseline (252.276 us; speedup 1.0000x reference)
//
#include <hip/hip_runtime.h>
#include <cstdint>
#include <cstddef>

// Problem dims (fixed by reference): x [8,1024,1024] -> M=8192, dim=1024, hidden=4096
#define DIM   1024
#define HID   4096
#define MROWS 8192

typedef __attribute__((ext_vector_type(8))) __bf16 bf16x8;
typedef __attribute__((ext_vector_type(4))) float  f32x4;
typedef __attribute__((ext_vector_type(4))) int    i32x4;

__device__ __forceinline__ unsigned short f2bf(float f) {
  unsigned int u = __float_as_uint(f);
  u += 0x7fffu + ((u >> 16) & 1u);   // round-to-nearest-even
  return (unsigned short)(u >> 16);
}
__device__ __forceinline__ float bf2f(unsigned int lo16) {
  return __uint_as_float(lo16 << 16);
}

// tanh-form GELU: ~7 VALU instrs vs ~25 for erff; deviation from exact ~1e-3.
__device__ __forceinline__ float fast_gelu(float v) {
  float u = v * (0.79788456080286536f + 0.035677408136300125f * v * v);
  float e = __builtin_amdgcn_exp2f(u * 2.8853900817779268f);   // exp(2u)
  float r = __builtin_amdgcn_rcpf(e + 1.0f);
  return v - v * r;   // = v * e/(e+1) = 0.5 v (1+tanh(u))
}

// ---- async global->LDS, 16B per lane (m97 pattern) ----
__device__ __forceinline__ void gld16(const void* g, void* l) {
  auto* gp = reinterpret_cast<__attribute__((address_space(1))) unsigned int*>(
      reinterpret_cast<uintptr_t>(g));
  auto* lp = reinterpret_cast<__attribute__((address_space(3))) unsigned int*>(
      reinterpret_cast<uintptr_t>(l));
  __builtin_amdgcn_global_load_lds(gp, lp, 16, 0, 0);
}

// ---- wave reduce (two values), 64 lanes, shuffle-only ----
__device__ __forceinline__ void wave_reduce2(float& a, float& b) {
#pragma unroll
  for (int off = 32; off > 0; off >>= 1) {
    a += __shfl_xor(a, off, 64);
    b += __shfl_xor(b, off, 64);
  }
}
__device__ __forceinline__ float wave_reduce_max(float m) {
#pragma unroll
  for (int off = 32; off > 0; off >>= 1) m = fmaxf(m, __shfl_xor(m, off, 64));
  return m;
}

// ---- block reduce (two values), 256 threads = 4 waves ----
__device__ __forceinline__ void block_reduce2(float& a, float& b, int tid) {
  __shared__ float red[8];
  __syncthreads();
  wave_reduce2(a, b);
  if ((tid & 63) == 0) { red[tid >> 6] = a; red[4 + (tid >> 6)] = b; }
  __syncthreads();
  a = red[0] + red[1] + red[2] + red[3];
  b = red[4] + red[5] + red[6] + red[7];
}

// ---- prep: |w| partial sums AND LN1(+i8 quant), one dispatch ----
__global__ __launch_bounds__(256)
void prep_kernel(const float* __restrict__ w1, const float* __restrict__ w2,
                 float* __restrict__ part,
                 const float* __restrict__ x, const float* __restrict__ g,
                 const float* __restrict__ b, unsigned int* __restrict__ xn8,
                 float* __restrict__ invs) {
  int tid = threadIdx.x;
  int bid = blockIdx.x;
  if (bid < 2048) {
    const float* w = (bid < 1024) ? w1 : w2;
    int blk = bid & 1023;
    const float4* base = (const float4*)w + (size_t)blk * 1024;
    float s = 0.f;
#pragma unroll
    for (int i = 0; i < 4; ++i) {
      float4 v = base[tid + i * 256];
      s += fabsf(v.x) + fabsf(v.y) + fabsf(v.z) + fabsf(v.w);
    }
#pragma unroll
    for (int off = 32; off > 0; off >>= 1) s += __shfl_xor(s, off, 64);
    __shared__ float red[4];
    if ((tid & 63) == 0) red[tid >> 6] = s;
    __syncthreads();
    if (tid == 0) part[bid] = red[0] + red[1] + red[2] + red[3];
  } else {
    const int row  = (bid - 2048) * 4 + (tid >> 6);
    const int lane = tid & 63;
    const float4* xr = (const float4*)(x + (size_t)row * DIM);
    const float4* g4 = (const float4*)g;
    const float4* b4 = (const float4*)b;
    float4 v[4];
    float s = 0.f, ss = 0.f;
#pragma unroll
    for (int p = 0; p < 4; ++p) {
      v[p] = xr[lane + 64 * p];
      s  += v[p].x + v[p].y + v[p].z + v[p].w;
      ss += v[p].x * v[p].x + v[p].y * v[p].y + v[p].z * v[p].z + v[p].w * v[p].w;
    }
    wave_reduce2(s, ss);
    float mu  = s * (1.0f / DIM);
    float var = ss * (1.0f / DIM) - mu * mu;
    float rs  = rsqrtf(var + 1e-5f);
    float n[4][4];
    float amax = 0.f;
#pragma unroll
    for (int p = 0; p < 4; ++p) {
      float4 gg = g4[lane + 64 * p];
      float4 bb = b4[lane + 64 * p];
      n[p][0] = (v[p].x - mu) * rs * gg.x + bb.x;
      n[p][1] = (v[p].y - mu) * rs * gg.y + bb.y;
      n[p][2] = (v[p].z - mu) * rs * gg.z + bb.z;
      n[p][3] = (v[p].w - mu) * rs * gg.w + bb.w;
#pragma unroll
      for (int c = 0; c < 4; ++c) amax = fmaxf(amax, fabsf(n[p][c]));
    }
    amax = wave_reduce_max(amax);
    float sc, iv;
    if (amax < 1e-20f) { sc = 0.f; iv = 0.f; }
    else               { sc = 127.0f / amax; iv = amax * (1.0f / 127.0f); }
    if (lane == 0) invs[row] = iv;
    unsigned int* dst = xn8 + (size_t)row * 256;   // 1024 i8 = 256 u32 per row
#pragma unroll
    for (int p = 0; p < 4; ++p) {
      unsigned r = 0;
#pragma unroll
      for (int c = 0; c < 4; ++c) {
        int q = (int)rintf(n[p][c] * sc);
        r |= ((unsigned)q & 0xffu) << (8 * c);
      }
      dst[lane + 64 * p] = r;
    }
  }
}

// ---- ternary quantize + folded-LN2 weight vectors ----
__global__ __launch_bounds__(256)
void quant_kernel(const float* __restrict__ part,
                  const float* __restrict__ w1, unsigned int* __restrict__ q1,
                  const float* __restrict__ w2, unsigned short* __restrict__ q2,
                  const float* __restrict__ g2, const float* __restrict__ b2,
                  const float* __restrict__ bias2,
                  float* __restrict__ Sg, float* __restrict__ Cb,
                  float* __restrict__ scal) {
  int bid = blockIdx.x, tid = threadIdx.x;
  const int lane = tid & 63;
  const float4* psrc = (const float4*)(part + ((bid < 512) ? 0 : 1024));
  float a = 0.f, dummy = 0.f;
#pragma unroll
  for (int p = 0; p < 4; ++p) {
    float4 pv = psrc[lane + 64 * p];
    a += pv.x + pv.y + pv.z + pv.w;
  }
  wave_reduce2(a, dummy);
  float mean = fmaxf(a * (1.0f / 4194304.0f), 1e-5f);
  float sc = 1.0f / mean;

  if (bid < 512) {
    if (bid == 0 && tid == 0) scal[0] = mean;
    const int n4 = 1048576;
    int i = bid * 256 + tid;
    for (; i < n4; i += 512 * 256) {
      float4 v = ((const float4*)w1)[i];
      int t0 = (int)fminf(fmaxf(rintf(v.x * sc), -1.f), 1.f);
      int t1 = (int)fminf(fmaxf(rintf(v.y * sc), -1.f), 1.f);
      int t2 = (int)fminf(fmaxf(rintf(v.z * sc), -1.f), 1.f);
      int t3 = (int)fminf(fmaxf(rintf(v.w * sc), -1.f), 1.f);
      unsigned r = ((unsigned)t0 & 0xffu) | (((unsigned)t1 & 0xffu) << 8) |
                   (((unsigned)t2 & 0xffu) << 16) | (((unsigned)t3 & 0xffu) << 24);
      q1[i] = r;
    }
  } else {
    const int d = bid - 512;
    if (d == 0 && tid == 0) scal[1] = mean;
    const float4* wr = (const float4*)(w2 + (size_t)d * HID);
    const float4* g4 = (const float4*)g2;
    const float4* b4 = (const float4*)b2;
    uint2* qr = (uint2*)(q2 + (size_t)d * HID);
    float s1 = 0.f, s2 = 0.f;
#pragma unroll
    for (int i = 0; i < 4; ++i) {
      int idx = tid + 256 * i;
      float4 wv = wr[idx], gv = g4[idx], bv = b4[idx];
      float t0 = fminf(fmaxf(rintf(wv.x * sc), -1.f), 1.f);
      float t1 = fminf(fmaxf(rintf(wv.y * sc), -1.f), 1.f);
      float t2 = fminf(fmaxf(rintf(wv.z * sc), -1.f), 1.f);
      float t3 = fminf(fmaxf(rintf(wv.w * sc), -1.f), 1.f);
      s1 += gv.x * t0 + gv.y * t1 + gv.z * t2 + gv.w * t3;
      s2 += bv.x * t0 + bv.y * t1 + bv.z * t2 + bv.w * t3;
      uint2 r;
      r.x = (unsigned)f2bf(t0 * gv.x) | ((unsigned)f2bf(t1 * gv.y) << 16);
      r.y = (unsigned)f2bf(t2 * gv.z) | ((unsigned)f2bf(t3 * gv.w) << 16);
      qr[idx] = r;
    }
    block_reduce2(s1, s2, tid);
    if (tid == 0) {
      Sg[d] = mean * s1;
      Cb[d] = mean * s2 + bias2[d];
    }
  }
}

// ---- GEMM1 (i8) v3: dbuf LDS, ONE barrier + ONE vmcnt per K-tile.
// Row-stats fused WITHOUT atomics; each wave stores its private per-row
// partial (s,ss) as a plain float2 into sbuf2[row][2*col + wn] -- no RMW.
__global__ __launch_bounds__(256)
void gemm1_i8(const unsigned char* __restrict__ A,
              const unsigned char* __restrict__ B,
              unsigned short* __restrict__ H,
              const float* __restrict__ wscale_ptr,
              const float* __restrict__ invs,
              const float* __restrict__ bias,
              float2* __restrict__ sbuf2) {
  __shared__ unsigned char sA[2][128 * 64];
  __shared__ unsigned char sB[2][128 * 64];

  const int tid  = threadIdx.x;
  const int lane = tid & 63;
  const int wave = tid >> 6;
  const int wm   = wave & 1;
  const int wn   = wave >> 1;

  const int nbx  = gridDim.x;
  const int id   = blockIdx.y * nbx + blockIdx.x;
  const int xcd  = id & 7;
  const int slot = id >> 3;
  const int bandsPerXcd = gridDim.y >> 3;
  const int band = xcd * bandsPerXcd + slot / nbx;
  const int col  = slot - (slot / nbx) * nbx;
  const int bm   = band * 128;
  const int bn   = col * 128;

  const int csw = ((tid & 3) ^ ((tid >> 3) & 3)) * 16;
  const unsigned char* Ab = A + (size_t)(bm + (tid >> 2)) * 1024 + csw;
  const unsigned char* Bb = B + (size_t)(bn + (tid >> 2)) * 1024 + csw;

  i32x4 acc[4][4] = {};

  const int rowA = (wm * 64 + (lane & 15)) * 64;
  const int rowB = (wn * 64 + (lane & 15)) * 64;
  const int kc = (((lane >> 4) ^ ((lane >> 1) & 3))) * 16;

  // prologue: stage tile 0 -> buf0
  gld16(Ab,             (char*)&sA[0][0] + tid * 16);
  gld16(Ab + 64 * 1024, (char*)&sA[0][0] + 4096 + tid * 16);
  gld16(Bb,             (char*)&sB[0][0] + tid * 16);
  gld16(Bb + 64 * 1024, (char*)&sB[0][0] + 4096 + tid * 16);
  asm volatile("s_waitcnt vmcnt(0)" ::: "memory");
  __builtin_amdgcn_s_barrier();

  for (int t = 0; t < 16; ++t) {
    const int cur = t & 1;
    const size_t kn = (t + 1 < 16) ? (size_t)(t + 1) * 64 : 0;   // clamp = junk, never read
    gld16(Ab + kn,             (char*)&sA[cur ^ 1][0] + tid * 16);
    gld16(Ab + 64 * 1024 + kn, (char*)&sA[cur ^ 1][0] + 4096 + tid * 16);
    gld16(Bb + kn,             (char*)&sB[cur ^ 1][0] + tid * 16);
    gld16(Bb + 64 * 1024 + kn, (char*)&sB[cur ^ 1][0] + 4096 + tid * 16);
    const unsigned char* a = &sA[cur][0];
    const unsigned char* b = &sB[cur][0];
    i32x4 af[4], bfr[4];
#pragma unroll
    for (int i = 0; i < 4; ++i) af[i]  = *(const i32x4*)(a + rowA + i * 1024 + kc);
#pragma unroll
    for (int j = 0; j < 4; ++j) bfr[j] = *(const i32x4*)(b + rowB + j * 1024 + kc);
    __builtin_amdgcn_s_setprio(1);
#pragma unroll
    for (int i = 0; i < 4; ++i)
#pragma unroll
      for (int j = 0; j < 4; ++j)
        acc[i][j] = __builtin_amdgcn_mfma_i32_16x16x64_i8(af[i], bfr[j], acc[i][j], 0, 0, 0);
    __builtin_amdgcn_s_setprio(0);
    asm volatile("s_waitcnt vmcnt(0)" ::: "memory");
    __builtin_amdgcn_s_barrier();
  }

  const float wscale = *wscale_ptr;
  float bv[4];
#pragma unroll
  for (int j = 0; j < 4; ++j) bv[j] = bias[bn + wn * 64 + j * 16 + (lane & 15)];
#pragma unroll
  for (int i = 0; i < 4; ++i) {
    const int m0 = bm + wm * 64 + i * 16 + ((lane >> 4) << 2);
    float asc[4];
#pragma unroll
    for (int r = 0; r < 4; ++r) asc[r] = wscale * invs[m0 + r];
#pragma unroll
    for (int r = 0; r < 4; ++r) {
      float s = 0.f, ss = 0.f;
#pragma unroll
      for (int j = 0; j < 4; ++j) {
        const int n = bn + wn * 64 + j * 16 + (lane & 15);
        float v = fast_gelu((float)acc[i][j][r] * asc[r] + bv[j]);
        H[(size_t)(m0 + r) * HID + n] = f2bf(v);
        s += v; ss += v * v;
      }
#pragma unroll
      for (int off = 1; off < 16; off <<= 1) {
        s  += __shfl_xor(s, off, 64);
        ss += __shfl_xor(ss, off, 64);
      }
      if ((lane & 15) == 0) {
        sbuf2[((size_t)(m0 + r) << 6) + (col << 1) + wn] = make_float2(s, ss);
      }
    }
  }
}

// ---- finalize per-row (a_m, b_m): reduce 64 partials per row ----
__global__ __launch_bounds__(256)
void murs_fin(const float2* __restrict__ sbuf2, const float* __restrict__ meanp,
              float2* __restrict__ murs) {
  const int row  = blockIdx.x * 4 + (threadIdx.x >> 6);
  const int lane = threadIdx.x & 63;
  float2 v = sbuf2[((size_t)row << 6) + lane];
  float s = v.x, ss = v.y;
  wave_reduce2(s, ss);
  if (lane == 0) {
    float mu  = s * (1.0f / HID);
    float var = ss * (1.0f / HID) - mu * mu;
    float rs  = rsqrtf(var + 1e-5f);
    murs[row] = make_float2(rs * meanp[1], -rs * mu);
  }
}

// ---- GEMM2 v4: K-split waves for 128x64 wave tiles ----
// R4 post-mortem: v3 measured 2614cy/tile vs MFMA floor 1242; binding term is
// LDS read volume 128KB/tile (~1500cy), set by wave-tile shape (64x64 ->
// 32 FLOP/LDS-byte). v4: 8 waves = 2M x 2N x 2K-split; each wave owns
// 128 rows x 64 cols x half the k-range (32 of each BK=64 tile) -> 42.7
// FLOP/B, LDS reads 96KB/tile (12 ds_read_b128/wave vs 16). Staging,
// swizzle (rule #21) and the proven v3 single-barrier schedule unchanged.
// Cost: acc 8x4 f32x4 (128 VGPR, ~200 total; cap 256 at 2 waves/SIMD) and
// a one-time cross-wave k-half reduction via the retired sA buffer.
__global__ __launch_bounds__(512, 2)
void gemm2_v4(const unsigned short* __restrict__ A,
              const unsigned short* __restrict__ B,
              float* __restrict__ C,
              const float2* __restrict__ murs,
              const float* __restrict__ Sg,
              const float* __restrict__ Cb) {
  __shared__ unsigned short sA[2][256 * 64];
  __shared__ unsigned short sB[2][128 * 64];

  const int tid  = threadIdx.x;
  const int lane = tid & 63;
  const int wave = tid >> 6;
  const int wn   = wave & 1;          // 0..1  (64-col half)
  const int wm   = (wave >> 1) & 1;   // 0..1  (128-row half)
  const int wk   = wave >> 2;         // 0..1  (k-half of each BK=64 tile)

  // XCD-aware remap: 256 blocks (32 bands x 8 cols), 4 bands/XCD. Bijective.
  const int id   = blockIdx.y * 8 + blockIdx.x;
  const int xcd  = id & 7;
  const int slot = id >> 3;
  const int band = xcd * 4 + (slot >> 3);
  const int col  = slot & 7;
  const int bm   = band * 256;
  const int bn   = col * 128;

  // staging: linear LDS dest + pre-swizzled global source (rule #21)
  const int csw = ((tid & 7) ^ ((tid >> 3) & 7)) << 3;     // elements
  const unsigned short* Ab = A + (size_t)(bm + (tid >> 3)) * 4096 + csw;
  const unsigned short* Bb = B + (size_t)(bn + (tid >> 3)) * 4096 + csw;

  // fragment reads: row = wbase + frag*16 + (lane&15); logical k-chunk =
  // wk*4 + (lane>>4); phys chunk = logical ^ (row&7) = logical ^ (lane&7).
  const int rowAb = (wm * 128 + (lane & 15)) * 128;   // bytes (sA row = 128B)
  const int rowBb = (wn * 64  + (lane & 15)) * 128;
  const int hi    = lane >> 4;
  const int ck    = ((wk * 4 + hi) ^ (lane & 7)) << 4;   // single k-slice, bytes

  f32x4 acc[8][4] = {};

  // prologue: stage tile 0 -> buf0
#pragma unroll
  for (int i = 0; i < 4; ++i) gld16(Ab + (size_t)i * 262144, (char*)&sA[0][0] + i * 8192 + tid * 16);
#pragma unroll
  for (int i = 0; i < 2; ++i) gld16(Bb + (size_t)i * 262144, (char*)&sB[0][0] + i * 8192 + tid * 16);
  asm volatile("s_waitcnt vmcnt(0)" ::: "memory");
  __builtin_amdgcn_s_barrier();

  for (int t = 0; t < 64; ++t) {
    const int cur = t & 1;
    const size_t kn = (t + 1 < 64) ? (size_t)(t + 1) * 64 : 0;   // clamp = junk, never read
    // 1. issue stage(t+1) -> buf^1
#pragma unroll
    for (int i = 0; i < 4; ++i)
      gld16(Ab + (size_t)i * 262144 + kn, (char*)&sA[cur ^ 1][0] + i * 8192 + tid * 16);
#pragma unroll
    for (int i = 0; i < 2; ++i)
      gld16(Bb + (size_t)i * 262144 + kn, (char*)&sB[cur ^ 1][0] + i * 8192 + tid * 16);
    // 2.+3. fragment reads (12 ds_read_b128) interleaved with 32 MFMA
    const char* a = (const char*)&sA[cur][0];
    const char* b = (const char*)&sB[cur][0];
    bf16x8 bfr[4];
#pragma unroll
    for (int j = 0; j < 4; ++j) bfr[j] = *(const bf16x8*)(b + rowBb + j * 2048 + ck);
#pragma unroll
    for (int h2 = 0; h2 < 2; ++h2) {
      bf16x8 af[4];
#pragma unroll
      for (int i = 0; i < 4; ++i)
        af[i] = *(const bf16x8*)(a + rowAb + (h2 * 4 + i) * 2048 + ck);
      __builtin_amdgcn_s_setprio(1);
#pragma unroll
      for (int i = 0; i < 4; ++i)
#pragma unroll
        for (int j = 0; j < 4; ++j)
          acc[h2 * 4 + i][j] =
              __builtin_amdgcn_mfma_f32_16x16x32_bf16(af[i], bfr[j], acc[h2 * 4 + i][j], 0, 0, 0);
      __builtin_amdgcn_s_setprio(0);
    }
    // 4. stage(t+1) landed (MFMA span covered latency); release buffers
    asm volatile("s_waitcnt vmcnt(0)" ::: "memory");
    __builtin_amdgcn_s_barrier();
  }

  // ---- epilogue: reduce wk pairs via retired sA (64KB), then store.
  // Pair (wm,wn): wk=1 writes acc, wk=0 adds and stores. 2 rounds by wm
  // (2 waves x 32KB = 64KB per round). Lane layout: per (i,j) frag, 64
  // lanes x 16B contiguous -> conflict-free.
  float sg[4], cb[4];
#pragma unroll
  for (int j = 0; j < 4; ++j) {
    const int n = bn + wn * 64 + j * 16 + (lane & 15);
    sg[j] = Sg[n];
    cb[j] = Cb[n];
  }
  float* red = (float*)&sA[0][0];
  for (int round = 0; round < 2; ++round) {
    __builtin_amdgcn_s_barrier();
    if (wk == 1 && wm == round) {
#pragma unroll
      for (int i = 0; i < 8; ++i)
#pragma unroll
        for (int j = 0; j < 4; ++j)
          *(f32x4*)(red + wn * 8192 + (i * 4 + j) * 256 + lane * 4) = acc[i][j];
    }
    __builtin_amdgcn_s_barrier();
    if (wk == 0 && wm == round) {
#pragma unroll
      for (int i = 0; i < 8; ++i) {
        const int m0 = bm + wm * 128 + i * 16 + (hi << 2);
#pragma unroll
        for (int j = 0; j < 4; ++j)
          acc[i][j] += *(const f32x4*)(red + wn * 8192 + (i * 4 + j) * 256 + lane * 4);
#pragma unroll
        for (int r = 0; r < 4; ++r) {
          float2 ab = murs[m0 + r];
#pragma unroll
          for (int j = 0; j < 4; ++j) {
            const int n = bn + wn * 64 + j * 16 + (lane & 15);
            C[(size_t)(m0 + r) * 1024 + n] = ab.x * acc[i][j][r] + ab.y * sg[j] + cb[j];
          }
        }
      }
    }
  }
}

extern "C" void kernel_launch(void* const* d_in, const int* in_sizes, int n_in,
                              void* d_out, int out_size, void* d_ws, size_t ws_size,
                              hipStream_t stream) {
  const float* x     = (const float*)d_in[0];
  const float* g1    = (const float*)d_in[1];
  const float* b1v   = (const float*)d_in[2];
  const float* w1    = (const float*)d_in[3];
  const float* bias1 = (const float*)d_in[4];
  const float* g2    = (const float*)d_in[5];
  const float* b2v   = (const float*)d_in[6];
  const float* w2    = (const float*)d_in[7];
  const float* bias2 = (const float*)d_in[8];
  float* out = (float*)d_out;

  char* ws = (char*)d_ws;
  float* scal          = (float*)ws;                      // [0]=mean|w1| [1]=mean|w2|
  float* part          = (float*)(ws + 64);               // 2048 partials
  float* invs          = (float*)(ws + 16384);            // 8192 per-row dequant (32 KB)
  unsigned int* q1     = (unsigned int*)(ws + 65536);     // 4096x1024 i8 = 4 MB
  unsigned short* q2   = (unsigned short*)(ws + 65536 + 4194304);  // 8 MB bf16
  unsigned int* xn8    = (unsigned int*)((char*)q2 + 8388608);     // 8192x1024 i8 = 8 MB
  unsigned short* h    = (unsigned short*)((char*)xn8 + 8388608);  // 64 MB bf16
  float2* murs         = (float2*)((char*)h + 67108864);  // 8192 x {a_m,b_m}
  float* Sg            = (float*)(murs + 8192);           // 1024
  float* Cb            = Sg + 1024;                       // 1024
  float2* sbuf2        = (float2*)(Cb + 1024);            // 8192 x 64 partials = 4 MB

  prep_kernel<<<4096, 256, 0, stream>>>(w1, w2, part, x, g1, b1v, xn8, invs);
  quant_kernel<<<1536, 256, 0, stream>>>(part, w1, q1, w2, q2, g2, b2v, bias2, Sg, Cb, scal);
  gemm1_i8<<<dim3(HID / 128, MROWS / 128), 256, 0, stream>>>(
      (const unsigned char*)xn8, (const unsigned char*)q1, h, scal + 0, invs, bias1, sbuf2);
  murs_fin<<<MROWS / 4, 256, 0, stream>>>(sbuf2, scal, murs);
  gemm2_v4<<<dim3(8, 32), 512, 0, stream>>>(h, q2, out, murs, Sg, Cb);
}

// Round 6
// 242.105 us; speedup vs baseline: 1.0420x; 1.0420x over previous
//
#include <hip/hip_runtime.h>
#include <cstdint>
#include <cstddef>

// Problem dims (fixed by reference): x [8,1024,1024] -> M=8192, dim=1024, hidden=4096
#define DIM   1024
#define HID   4096
#define MROWS 8192

typedef __attribute__((ext_vector_type(8))) __bf16 bf16x8;
typedef __attribute__((ext_vector_type(4))) float  f32x4;
typedef __attribute__((ext_vector_type(4))) int    i32x4;

__device__ __forceinline__ unsigned short f2bf(float f) {
  unsigned int u = __float_as_uint(f);
  u += 0x7fffu + ((u >> 16) & 1u);   // round-to-nearest-even
  return (unsigned short)(u >> 16);
}
__device__ __forceinline__ float bf2f(unsigned int lo16) {
  return __uint_as_float(lo16 << 16);
}

// tanh-form GELU: ~7 VALU instrs vs ~25 for erff; deviation from exact ~1e-3.
__device__ __forceinline__ float fast_gelu(float v) {
  float u = v * (0.79788456080286536f + 0.035677408136300125f * v * v);
  float e = __builtin_amdgcn_exp2f(u * 2.8853900817779268f);   // exp(2u)
  float r = __builtin_amdgcn_rcpf(e + 1.0f);
  return v - v * r;   // = v * e/(e+1) = 0.5 v (1+tanh(u))
}

// ---- async global->LDS, 16B per lane (m97 pattern) ----
__device__ __forceinline__ void gld16(const void* g, void* l) {
  auto* gp = reinterpret_cast<__attribute__((address_space(1))) unsigned int*>(
      reinterpret_cast<uintptr_t>(g));
  auto* lp = reinterpret_cast<__attribute__((address_space(3))) unsigned int*>(
      reinterpret_cast<uintptr_t>(l));
  __builtin_amdgcn_global_load_lds(gp, lp, 16, 0, 0);
}

// ---- wave reduce (two values), 64 lanes, shuffle-only ----
__device__ __forceinline__ void wave_reduce2(float& a, float& b) {
#pragma unroll
  for (int off = 32; off > 0; off >>= 1) {
    a += __shfl_xor(a, off, 64);
    b += __shfl_xor(b, off, 64);
  }
}
__device__ __forceinline__ float wave_reduce_max(float m) {
#pragma unroll
  for (int off = 32; off > 0; off >>= 1) m = fmaxf(m, __shfl_xor(m, off, 64));
  return m;
}

// ---- block reduce (two values), 256 threads = 4 waves ----
__device__ __forceinline__ void block_reduce2(float& a, float& b, int tid) {
  __shared__ float red[8];
  __syncthreads();
  wave_reduce2(a, b);
  if ((tid & 63) == 0) { red[tid >> 6] = a; red[4 + (tid >> 6)] = b; }
  __syncthreads();
  a = red[0] + red[1] + red[2] + red[3];
  b = red[4] + red[5] + red[6] + red[7];
}

// ---- prep: |w| partial sums AND LN1(+i8 quant), one dispatch ----
__global__ __launch_bounds__(256)
void prep_kernel(const float* __restrict__ w1, const float* __restrict__ w2,
                 float* __restrict__ part,
                 const float* __restrict__ x, const float* __restrict__ g,
                 const float* __restrict__ b, unsigned int* __restrict__ xn8,
                 float* __restrict__ invs) {
  int tid = threadIdx.x;
  int bid = blockIdx.x;
  if (bid < 2048) {
    const float* w = (bid < 1024) ? w1 : w2;
    int blk = bid & 1023;
    const float4* base = (const float4*)w + (size_t)blk * 1024;
    float s = 0.f;
#pragma unroll
    for (int i = 0; i < 4; ++i) {
      float4 v = base[tid + i * 256];
      s += fabsf(v.x) + fabsf(v.y) + fabsf(v.z) + fabsf(v.w);
    }
#pragma unroll
    for (int off = 32; off > 0; off >>= 1) s += __shfl_xor(s, off, 64);
    __shared__ float red[4];
    if ((tid & 63) == 0) red[tid >> 6] = s;
    __syncthreads();
    if (tid == 0) part[bid] = red[0] + red[1] + red[2] + red[3];
  } else {
    const int row  = (bid - 2048) * 4 + (tid >> 6);
    const int lane = tid & 63;
    const float4* xr = (const float4*)(x + (size_t)row * DIM);
    const float4* g4 = (const float4*)g;
    const float4* b4 = (const float4*)b;
    float4 v[4];
    float s = 0.f, ss = 0.f;
#pragma unroll
    for (int p = 0; p < 4; ++p) {
      v[p] = xr[lane + 64 * p];
      s  += v[p].x + v[p].y + v[p].z + v[p].w;
      ss += v[p].x * v[p].x + v[p].y * v[p].y + v[p].z * v[p].z + v[p].w * v[p].w;
    }
    wave_reduce2(s, ss);
    float mu  = s * (1.0f / DIM);
    float var = ss * (1.0f / DIM) - mu * mu;
    float rs  = rsqrtf(var + 1e-5f);
    float n[4][4];
    float amax = 0.f;
#pragma unroll
    for (int p = 0; p < 4; ++p) {
      float4 gg = g4[lane + 64 * p];
      float4 bb = b4[lane + 64 * p];
      n[p][0] = (v[p].x - mu) * rs * gg.x + bb.x;
      n[p][1] = (v[p].y - mu) * rs * gg.y + bb.y;
      n[p][2] = (v[p].z - mu) * rs * gg.z + bb.z;
      n[p][3] = (v[p].w - mu) * rs * gg.w + bb.w;
#pragma unroll
      for (int c = 0; c < 4; ++c) amax = fmaxf(amax, fabsf(n[p][c]));
    }
    amax = wave_reduce_max(amax);
    float sc, iv;
    if (amax < 1e-20f) { sc = 0.f; iv = 0.f; }
    else               { sc = 127.0f / amax; iv = amax * (1.0f / 127.0f); }
    if (lane == 0) invs[row] = iv;
    unsigned int* dst = xn8 + (size_t)row * 256;   // 1024 i8 = 256 u32 per row
#pragma unroll
    for (int p = 0; p < 4; ++p) {
      unsigned r = 0;
#pragma unroll
      for (int c = 0; c < 4; ++c) {
        int q = (int)rintf(n[p][c] * sc);
        r |= ((unsigned)q & 0xffu) << (8 * c);
      }
      dst[lane + 64 * p] = r;
    }
  }
}

// ---- ternary quantize + folded-LN2 weight vectors ----
__global__ __launch_bounds__(256)
void quant_kernel(const float* __restrict__ part,
                  const float* __restrict__ w1, unsigned int* __restrict__ q1,
                  const float* __restrict__ w2, unsigned short* __restrict__ q2,
                  const float* __restrict__ g2, const float* __restrict__ b2,
                  const float* __restrict__ bias2,
                  float* __restrict__ Sg, float* __restrict__ Cb,
                  float* __restrict__ scal) {
  int bid = blockIdx.x, tid = threadIdx.x;
  const int lane = tid & 63;
  const float4* psrc = (const float4*)(part + ((bid < 512) ? 0 : 1024));
  float a = 0.f, dummy = 0.f;
#pragma unroll
  for (int p = 0; p < 4; ++p) {
    float4 pv = psrc[lane + 64 * p];
    a += pv.x + pv.y + pv.z + pv.w;
  }
  wave_reduce2(a, dummy);
  float mean = fmaxf(a * (1.0f / 4194304.0f), 1e-5f);
  float sc = 1.0f / mean;

  if (bid < 512) {
    if (bid == 0 && tid == 0) scal[0] = mean;
    const int n4 = 1048576;
    int i = bid * 256 + tid;
    for (; i < n4; i += 512 * 256) {
      float4 v = ((const float4*)w1)[i];
      int t0 = (int)fminf(fmaxf(rintf(v.x * sc), -1.f), 1.f);
      int t1 = (int)fminf(fmaxf(rintf(v.y * sc), -1.f), 1.f);
      int t2 = (int)fminf(fmaxf(rintf(v.z * sc), -1.f), 1.f);
      int t3 = (int)fminf(fmaxf(rintf(v.w * sc), -1.f), 1.f);
      unsigned r = ((unsigned)t0 & 0xffu) | (((unsigned)t1 & 0xffu) << 8) |
                   (((unsigned)t2 & 0xffu) << 16) | (((unsigned)t3 & 0xffu) << 24);
      q1[i] = r;
    }
  } else {
    const int d = bid - 512;
    if (d == 0 && tid == 0) scal[1] = mean;
    const float4* wr = (const float4*)(w2 + (size_t)d * HID);
    const float4* g4 = (const float4*)g2;
    const float4* b4 = (const float4*)b2;
    uint2* qr = (uint2*)(q2 + (size_t)d * HID);
    float s1 = 0.f, s2 = 0.f;
#pragma unroll
    for (int i = 0; i < 4; ++i) {
      int idx = tid + 256 * i;
      float4 wv = wr[idx], gv = g4[idx], bv = b4[idx];
      float t0 = fminf(fmaxf(rintf(wv.x * sc), -1.f), 1.f);
      float t1 = fminf(fmaxf(rintf(wv.y * sc), -1.f), 1.f);
      float t2 = fminf(fmaxf(rintf(wv.z * sc), -1.f), 1.f);
      float t3 = fminf(fmaxf(rintf(wv.w * sc), -1.f), 1.f);
      s1 += gv.x * t0 + gv.y * t1 + gv.z * t2 + gv.w * t3;
      s2 += bv.x * t0 + bv.y * t1 + bv.z * t2 + bv.w * t3;
      uint2 r;
      r.x = (unsigned)f2bf(t0 * gv.x) | ((unsigned)f2bf(t1 * gv.y) << 16);
      r.y = (unsigned)f2bf(t2 * gv.z) | ((unsigned)f2bf(t3 * gv.w) << 16);
      qr[idx] = r;
    }
    block_reduce2(s1, s2, tid);
    if (tid == 0) {
      Sg[d] = mean * s1;
      Cb[d] = mean * s2 + bias2[d];
    }
  }
}

// ---- GEMM1 (i8) v3: dbuf LDS, ONE barrier + ONE vmcnt per K-tile.
// Row-stats fused WITHOUT atomics; each wave stores its private per-row
// partial (s,ss) as a plain float2 into sbuf2[row][2*col + wn] -- no RMW.
__global__ __launch_bounds__(256)
void gemm1_i8(const unsigned char* __restrict__ A,
              const unsigned char* __restrict__ B,
              unsigned short* __restrict__ H,
              const float* __restrict__ wscale_ptr,
              const float* __restrict__ invs,
              const float* __restrict__ bias,
              float2* __restrict__ sbuf2) {
  __shared__ unsigned char sA[2][128 * 64];
  __shared__ unsigned char sB[2][128 * 64];

  const int tid  = threadIdx.x;
  const int lane = tid & 63;
  const int wave = tid >> 6;
  const int wm   = wave & 1;
  const int wn   = wave >> 1;

  const int nbx  = gridDim.x;
  const int id   = blockIdx.y * nbx + blockIdx.x;
  const int xcd  = id & 7;
  const int slot = id >> 3;
  const int bandsPerXcd = gridDim.y >> 3;
  const int band = xcd * bandsPerXcd + slot / nbx;
  const int col  = slot - (slot / nbx) * nbx;
  const int bm   = band * 128;
  const int bn   = col * 128;

  const int csw = ((tid & 3) ^ ((tid >> 3) & 3)) * 16;
  const unsigned char* Ab = A + (size_t)(bm + (tid >> 2)) * 1024 + csw;
  const unsigned char* Bb = B + (size_t)(bn + (tid >> 2)) * 1024 + csw;

  i32x4 acc[4][4] = {};

  const int rowA = (wm * 64 + (lane & 15)) * 64;
  const int rowB = (wn * 64 + (lane & 15)) * 64;
  const int kc = (((lane >> 4) ^ ((lane >> 1) & 3))) * 16;

  // prologue: stage tile 0 -> buf0
  gld16(Ab,             (char*)&sA[0][0] + tid * 16);
  gld16(Ab + 64 * 1024, (char*)&sA[0][0] + 4096 + tid * 16);
  gld16(Bb,             (char*)&sB[0][0] + tid * 16);
  gld16(Bb + 64 * 1024, (char*)&sB[0][0] + 4096 + tid * 16);
  asm volatile("s_waitcnt vmcnt(0)" ::: "memory");
  __builtin_amdgcn_s_barrier();

  for (int t = 0; t < 16; ++t) {
    const int cur = t & 1;
    const size_t kn = (t + 1 < 16) ? (size_t)(t + 1) * 64 : 0;   // clamp = junk, never read
    gld16(Ab + kn,             (char*)&sA[cur ^ 1][0] + tid * 16);
    gld16(Ab + 64 * 1024 + kn, (char*)&sA[cur ^ 1][0] + 4096 + tid * 16);
    gld16(Bb + kn,             (char*)&sB[cur ^ 1][0] + tid * 16);
    gld16(Bb + 64 * 1024 + kn, (char*)&sB[cur ^ 1][0] + 4096 + tid * 16);
    const unsigned char* a = &sA[cur][0];
    const unsigned char* b = &sB[cur][0];
    i32x4 af[4], bfr[4];
#pragma unroll
    for (int i = 0; i < 4; ++i) af[i]  = *(const i32x4*)(a + rowA + i * 1024 + kc);
#pragma unroll
    for (int j = 0; j < 4; ++j) bfr[j] = *(const i32x4*)(b + rowB + j * 1024 + kc);
    __builtin_amdgcn_s_setprio(1);
#pragma unroll
    for (int i = 0; i < 4; ++i)
#pragma unroll
      for (int j = 0; j < 4; ++j)
        acc[i][j] = __builtin_amdgcn_mfma_i32_16x16x64_i8(af[i], bfr[j], acc[i][j], 0, 0, 0);
    __builtin_amdgcn_s_setprio(0);
    asm volatile("s_waitcnt vmcnt(0)" ::: "memory");
    __builtin_amdgcn_s_barrier();
  }

  const float wscale = *wscale_ptr;
  float bv[4];
#pragma unroll
  for (int j = 0; j < 4; ++j) bv[j] = bias[bn + wn * 64 + j * 16 + (lane & 15)];
#pragma unroll
  for (int i = 0; i < 4; ++i) {
    const int m0 = bm + wm * 64 + i * 16 + ((lane >> 4) << 2);
    float asc[4];
#pragma unroll
    for (int r = 0; r < 4; ++r) asc[r] = wscale * invs[m0 + r];
#pragma unroll
    for (int r = 0; r < 4; ++r) {
      float s = 0.f, ss = 0.f;
#pragma unroll
      for (int j = 0; j < 4; ++j) {
        const int n = bn + wn * 64 + j * 16 + (lane & 15);
        float v = fast_gelu((float)acc[i][j][r] * asc[r] + bv[j]);
        H[(size_t)(m0 + r) * HID + n] = f2bf(v);
        s += v; ss += v * v;
      }
#pragma unroll
      for (int off = 1; off < 16; off <<= 1) {
        s  += __shfl_xor(s, off, 64);
        ss += __shfl_xor(ss, off, 64);
      }
      if ((lane & 15) == 0) {
        sbuf2[((size_t)(m0 + r) << 6) + (col << 1) + wn] = make_float2(s, ss);
      }
    }
  }
}

// ---- finalize per-row (a_m, b_m): reduce 64 partials per row ----
__global__ __launch_bounds__(256)
void murs_fin(const float2* __restrict__ sbuf2, const float* __restrict__ meanp,
              float2* __restrict__ murs) {
  const int row  = blockIdx.x * 4 + (threadIdx.x >> 6);
  const int lane = threadIdx.x & 63;
  float2 v = sbuf2[((size_t)row << 6) + lane];
  float s = v.x, ss = v.y;
  wave_reduce2(s, ss);
  if (lane == 0) {
    float mu  = s * (1.0f / HID);
    float var = ss * (1.0f / HID) - mu * mu;
    float rs  = rsqrtf(var + 1e-5f);
    murs[row] = make_float2(rs * meanp[1], -rs * mu);
  }
}

// ---- GEMM2 v5: v3 structure + T4 counted vmcnt via TRIPLE-buffered LDS ----
// R5 post-mortem: v4 (fewer LDS reads) was neutral-negative -> LDS volume is
// not binding. v3/v4/8ph all plateau 35-39% and all share a per-tile
// vmcnt(0)-or-near drain with 1 block/CU (no cross-block cover): the m233
// "stage+vmcnt+bar" stall. v5 keeps v3's single barrier/tile but NEVER drains:
// 3 LDS bufs (144KiB), tile t issues stage(t+2) -> buf[(t+2)%3], reads
// buf[t%3], then s_waitcnt vmcnt(6) retires exactly stage(t+1) (issued one
// full tile ago, ~2600cy of cover) while the 6 fresh loads stay in flight
// across the barrier (T4/m218: counted-vs-drain0 is THE 8-phase gain).
// Cross-wave: each wave vmcnt's its own loads; barrier makes buf[t+1] visible
// to all (m201 phase-4/8 pattern). WAR: buf[(t+2)%3] last read at t-1, reads
// consumed via lgkm before that barrier. Numerics identical to v3.
__global__ __launch_bounds__(512, 2)
void gemm2_v5(const unsigned short* __restrict__ A,
              const unsigned short* __restrict__ B,
              float* __restrict__ C,
              const float2* __restrict__ murs,
              const float* __restrict__ Sg,
              const float* __restrict__ Cb) {
  __shared__ unsigned short sA[3][256 * 64];   // 96 KiB
  __shared__ unsigned short sB[3][128 * 64];   // 48 KiB

  const int tid  = threadIdx.x;
  const int lane = tid & 63;
  const int wave = tid >> 6;
  const int wm   = wave >> 1;    // 0..3
  const int wn   = wave & 1;     // 0..1

  // XCD-aware remap: 256 blocks (32 bands x 8 cols), 4 bands/XCD. Bijective.
  const int id   = blockIdx.y * 8 + blockIdx.x;
  const int xcd  = id & 7;
  const int slot = id >> 3;
  const int band = xcd * 4 + (slot >> 3);
  const int col  = slot & 7;
  const int bm   = band * 256;
  const int bn   = col * 128;

  // staging: linear LDS dest + pre-swizzled global source (rule #21)
  const int csw = ((tid & 7) ^ ((tid >> 3) & 7)) << 3;     // elements
  const unsigned short* Ab = A + (size_t)(bm + (tid >> 3)) * 4096 + csw;
  const unsigned short* Bb = B + (size_t)(bn + (tid >> 3)) * 4096 + csw;

  // fragment reads: row = wbase + frag*16 + (lane&15); phys chunk = log ^ (lane&7)
  const int rowAb = (wm * 64 + (lane & 15)) * 128;   // bytes
  const int rowBb = (wn * 64 + (lane & 15)) * 128;
  const int hi    = lane >> 4;
  const int ck0   = ((hi)     ^ (lane & 7)) << 4;    // k-slice 0, bytes
  const int ck1   = ((hi + 4) ^ (lane & 7)) << 4;    // k-slice 1

  f32x4 acc[4][4] = {};

  // prologue: stage tile 0 -> buf0, tile 1 -> buf1; wait tile 0 only.
#pragma unroll
  for (int i = 0; i < 4; ++i) gld16(Ab + (size_t)i * 262144,      (char*)&sA[0][0] + i * 8192 + tid * 16);
#pragma unroll
  for (int i = 0; i < 2; ++i) gld16(Bb + (size_t)i * 262144,      (char*)&sB[0][0] + i * 8192 + tid * 16);
#pragma unroll
  for (int i = 0; i < 4; ++i) gld16(Ab + (size_t)i * 262144 + 64, (char*)&sA[1][0] + i * 8192 + tid * 16);
#pragma unroll
  for (int i = 0; i < 2; ++i) gld16(Bb + (size_t)i * 262144 + 64, (char*)&sB[1][0] + i * 8192 + tid * 16);
  asm volatile("s_waitcnt vmcnt(6)" ::: "memory");
  __builtin_amdgcn_s_barrier();

  int cur = 0, nx2 = 2;   // buf index of tile t and of tile t+2 (rotating mod 3)
  for (int t = 0; t < 64; ++t) {
    const size_t kn = (t + 2 < 64) ? (size_t)(t + 2) * 64 : 0;   // clamp = junk, never read
    // 1. issue stage(t+2) -> buf[nx2] (disjoint from read buf; last read at t-1)
    char* la = (char*)&sA[0][0] + nx2 * 32768;
    char* lb = (char*)&sB[0][0] + nx2 * 16384;
#pragma unroll
    for (int i = 0; i < 4; ++i) gld16(Ab + (size_t)i * 262144 + kn, la + i * 8192 + tid * 16);
#pragma unroll
    for (int i = 0; i < 2; ++i) gld16(Bb + (size_t)i * 262144 + kn, lb + i * 8192 + tid * 16);
    // 2. all 16 fragment reads from buf[cur]
    const char* a = (const char*)&sA[0][0] + cur * 32768;
    const char* b = (const char*)&sB[0][0] + cur * 16384;
    bf16x8 af[4][2], bfr[4][2];
#pragma unroll
    for (int i = 0; i < 4; ++i) {
      af[i][0] = *(const bf16x8*)(a + rowAb + i * 2048 + ck0);
      af[i][1] = *(const bf16x8*)(a + rowAb + i * 2048 + ck1);
    }
#pragma unroll
    for (int j = 0; j < 4; ++j) {
      bfr[j][0] = *(const bf16x8*)(b + rowBb + j * 2048 + ck0);
      bfr[j][1] = *(const bf16x8*)(b + rowBb + j * 2048 + ck1);
    }
    // 3. 32 MFMA (k-slice 0 cluster first; compiler inserts counted lgkm waits)
    __builtin_amdgcn_s_setprio(1);
#pragma unroll
    for (int i = 0; i < 4; ++i)
#pragma unroll
      for (int j = 0; j < 4; ++j)
        acc[i][j] = __builtin_amdgcn_mfma_f32_16x16x32_bf16(af[i][0], bfr[j][0], acc[i][j], 0, 0, 0);
#pragma unroll
    for (int i = 0; i < 4; ++i)
#pragma unroll
      for (int j = 0; j < 4; ++j)
        acc[i][j] = __builtin_amdgcn_mfma_f32_16x16x32_bf16(af[i][1], bfr[j][1], acc[i][j], 0, 0, 0);
    __builtin_amdgcn_s_setprio(0);
    // 4. COUNTED wait: retire stage(t+1) (issued last tile), keep the 6 fresh
    //    loads in flight across the barrier. Never drains to 0 in the loop.
    asm volatile("s_waitcnt vmcnt(6)" ::: "memory");
    __builtin_amdgcn_s_barrier();
    cur = (cur == 2) ? 0 : cur + 1;
    nx2 = (nx2 == 2) ? 0 : nx2 + 1;
  }
  // drain the tail junk prefetches before LDS reuse / exit
  asm volatile("s_waitcnt vmcnt(0)" ::: "memory");

  // ---- epilogue: out = a_m*acc + b_m*Sg[n] + Cb[n]
  float sg[4], cb[4];
#pragma unroll
  for (int j = 0; j < 4; ++j) {
    const int n = bn + wn * 64 + j * 16 + (lane & 15);
    sg[j] = Sg[n];
    cb[j] = Cb[n];
  }
#pragma unroll
  for (int i = 0; i < 4; ++i) {
    const int m0 = bm + wm * 64 + i * 16 + (hi << 2);
#pragma unroll
    for (int r = 0; r < 4; ++r) {
      float2 ab = murs[m0 + r];
#pragma unroll
      for (int j = 0; j < 4; ++j) {
        const int n = bn + wn * 64 + j * 16 + (lane & 15);
        C[(size_t)(m0 + r) * 1024 + n] = ab.x * acc[i][j][r] + ab.y * sg[j] + cb[j];
      }
    }
  }
}

extern "C" void kernel_launch(void* const* d_in, const int* in_sizes, int n_in,
                              void* d_out, int out_size, void* d_ws, size_t ws_size,
                              hipStream_t stream) {
  const float* x     = (const float*)d_in[0];
  const float* g1    = (const float*)d_in[1];
  const float* b1v   = (const float*)d_in[2];
  const float* w1    = (const float*)d_in[3];
  const float* bias1 = (const float*)d_in[4];
  const float* g2    = (const float*)d_in[5];
  const float* b2v   = (const float*)d_in[6];
  const float* w2    = (const float*)d_in[7];
  const float* bias2 = (const float*)d_in[8];
  float* out = (float*)d_out;

  char* ws = (char*)d_ws;
  float* scal          = (float*)ws;                      // [0]=mean|w1| [1]=mean|w2|
  float* part          = (float*)(ws + 64);               // 2048 partials
  float* invs          = (float*)(ws + 16384);            // 8192 per-row dequant (32 KB)
  unsigned int* q1     = (unsigned int*)(ws + 65536);     // 4096x1024 i8 = 4 MB
  unsigned short* q2   = (unsigned short*)(ws + 65536 + 4194304);  // 8 MB bf16
  unsigned int* xn8    = (unsigned int*)((char*)q2 + 8388608);     // 8192x1024 i8 = 8 MB
  unsigned short* h    = (unsigned short*)((char*)xn8 + 8388608);  // 64 MB bf16
  float2* murs         = (float2*)((char*)h + 67108864);  // 8192 x {a_m,b_m}
  float* Sg            = (float*)(murs + 8192);           // 1024
  float* Cb            = Sg + 1024;                       // 1024
  float2* sbuf2        = (float2*)(Cb + 1024);            // 8192 x 64 partials = 4 MB

  prep_kernel<<<4096, 256, 0, stream>>>(w1, w2, part, x, g1, b1v, xn8, invs);
  quant_kernel<<<1536, 256, 0, stream>>>(part, w1, q1, w2, q2, g2, b2v, bias2, Sg, Cb, scal);
  gemm1_i8<<<dim3(HID / 128, MROWS / 128), 256, 0, stream>>>(
      (const unsigned char*)xn8, (const unsigned char*)q1, h, scal + 0, invs, bias1, sbuf2);
  murs_fin<<<MROWS / 4, 256, 0, stream>>>(sbuf2, scal, murs);
  gemm2_v5<<<dim3(8, 32), 512, 0, stream>>>(h, q2, out, murs, Sg, Cb);
}